// Round 6
// baseline (385.920 us; speedup 1.0000x reference)
//
#include <hip/hip_runtime.h>

// LSTM B=2048, T=1024, H=50. Round 19: clean 4-wave test (R17 minus poisons).
//  - 4 waves (256 thr), BW=8, 1 block/CU, grid=256. Each wave owns 4 gate-row
//    tiles (NTILE=4); lane (kq, dup=L15>>3, bl=L15&7) keeps TWO units:
//    uA = 16w + 4*dup + kq (acc a_dup), uB = uA + 8 (acc a_{dup+2}).
//  - vs R17: x comes from LDS XT (prefetched, off-chain) NOT per-step global
//    loads; h written as TWO plain ds_write_b16 at identity slots (R18's
//    proven conflict-profile) NOT packed-b32 at remapped slots.
//  - Mechanism under test: per-CU LDS-pipe queueing + barrier skew scale with
//    wave count (8 ds_read_b128/step vs R18's 14; 4-wave barrier vs 7).
//  - Keeps all R18 wins: zc C-operand init (exact f32 gx, accs a0,a1<-zcA,
//    a2,a3<-zcB; discarded-row zc values are don't-care), chained split-K,
//    exp2-only epilogue with pre-scaled c2 = 2*log2e*c, KP=80, one barrier
//    per step, x2 unrolled halves. Pad units (>=50) self-zero exactly.

#define H     50
#define TT    1024
#define BATCH 2048
#define BW    8
#define NTHR  256     // 4 waves
#define NTILE 4
#define KP    80      // f16 per hb row (40-word stride)

typedef float    f32x4 __attribute__((ext_vector_type(4)));
typedef _Float16 f16x8 __attribute__((ext_vector_type(8)));

__global__ __launch_bounds__(NTHR, 1) void lstm_kernel(
    const float* __restrict__ x,      // [B, T]
    const float* __restrict__ W_ih,   // [200]
    const float* __restrict__ W_hh,   // [200, 50]
    const float* __restrict__ b_ih,   // [200]
    const float* __restrict__ b_hh,   // [200]
    const float* __restrict__ W_lin,  // [50]
    const float* __restrict__ b_lin,  // [1]
    float* __restrict__ out)          // [B]
{
    __shared__ _Float16 hb[2][BW][KP];    // h^T (slot = unit), double-buffered
    __shared__ float    XT[TT + 2][BW];   // x per (t, b), +2 pad rows
    __shared__ float    redH[H][BW];      // head reduction

    const int tid  = threadIdx.x;
    const int wave = tid >> 6;
    const int lane = tid & 63;
    const int L15  = lane & 15;
    const int kq   = lane >> 4;
    const int dup  = L15 >> 3;
    const int bl   = L15 & 7;
    const int b0   = blockIdx.x * BW;

    const float LOG2E  = 1.4426950408889634f;
    const float LOG2E2 = 2.8853900817779268f;

    // ---- A fragments: 4 tiles (rows n' = 4j+g), scaled f16 W_hh ----
    f16x8 A[NTILE][2];
    #pragma unroll
    for (int tt = 0; tt < NTILE; ++tt) {
        const int m  = (NTILE * wave + tt) * 16 + L15;
        const int jm = m >> 2, gm = m & 3;
        const bool v = (jm < H);
        const float s = (gm == 2) ? LOG2E2 : -LOG2E;
        #pragma unroll
        for (int kf = 0; kf < 2; ++kf) {
            f16x8 vv;
            #pragma unroll
            for (int e = 0; e < 8; ++e) {
                const int k = kf * 32 + kq * 8 + e;
                _Float16 val = (_Float16)0.f;
                if (v && k < H) val = (_Float16)(s * W_hh[(gm * H + jm) * H + k]);
                vv[e] = val;
            }
            A[tt][kf] = vv;
        }
    }

    // ---- this lane's 2 units + exact f32 x-path coefficients ----
    const int  uA  = 16 * wave + 4 * dup + kq;   // acc a_dup
    const int  uB  = uA + 8;                     // acc a_{dup+2}
    const bool vA  = (uA < H);
    const bool vB  = (uB < H);
    float zwA[4], zbA[4], zwB[4], zbB[4];
    #pragma unroll
    for (int r = 0; r < 4; ++r) {
        const float s = (r == 2) ? LOG2E2 : -LOG2E;
        zwA[r] = vA ? s * W_ih[r * H + uA] : 0.f;
        zbA[r] = vA ? s * (b_ih[r * H + uA] + b_hh[r * H + uA]) : 0.f;
        zwB[r] = vB ? s * W_ih[r * H + uB] : 0.f;
        zbB[r] = vB ? s * (b_ih[r * H + uB] + b_hh[r * H + uB]) : 0.f;
    }
    const float wlA = vA ? W_lin[uA] : 0.f;
    const float wlB = vB ? W_lin[uB] : 0.f;

    // ---- init: zero hb; fill XT from global x (coalesced in t) ----
    for (int i = tid; i < 2 * BW * KP; i += NTHR)
        ((_Float16*)hb)[i] = (_Float16)0.f;
    for (int i = tid; i < TT * BW; i += NTHR) {
        const int bb = i >> 10, t = i & 1023;
        XT[t][bb] = x[(size_t)(b0 + bb) * TT + t];
    }
    if (tid < 2 * BW) ((float*)&XT[TT][0])[tid] = 0.f;   // pad rows

    float c2A = 0.f, c2B = 0.f;        // scaled cell states (2*log2e*c)
    float hA = 0.f, hB = 0.f;
    __syncthreads();

    float xt_cur = XT[0][bl];
    const bool db = (dup != 0);

    #pragma unroll 1
    for (int tbase = 0; tbase < TT; tbase += 2) {
        #pragma unroll
        for (int half = 0; half < 2; ++half) {
            const int t = tbase + half;
            const _Float16* hp = &hb[half][bl][0];        // cur buffer
            _Float16*       np = &hb[half ^ 1][bl][0];    // next buffer

            // ---- B fragments: 2x ds_read_b128 ----
            const f16x8 B0 = *(const f16x8*)(hp + kq * 8);
            const f16x8 B1 = *(const f16x8*)(hp + 32 + kq * 8);

            // ---- C-init: exact f32 gx for this lane's 2 units ----
            f32x4 zcA, zcB;
            #pragma unroll
            for (int r = 0; r < 4; ++r) {
                zcA[r] = __builtin_fmaf(zwA[r], xt_cur, zbA[r]);
                zcB[r] = __builtin_fmaf(zwB[r], xt_cur, zbB[r]);
            }

            // ---- 8 MFMAs: 4 independent 2-deep split-K chains ----
            f32x4 a0 = __builtin_amdgcn_mfma_f32_16x16x32_f16(A[0][0], B0, zcA, 0, 0, 0);
            f32x4 a1 = __builtin_amdgcn_mfma_f32_16x16x32_f16(A[1][0], B0, zcA, 0, 0, 0);
            f32x4 a2 = __builtin_amdgcn_mfma_f32_16x16x32_f16(A[2][0], B0, zcB, 0, 0, 0);
            f32x4 a3 = __builtin_amdgcn_mfma_f32_16x16x32_f16(A[3][0], B0, zcB, 0, 0, 0);
            a0 = __builtin_amdgcn_mfma_f32_16x16x32_f16(A[0][1], B1, a0, 0, 0, 0);
            a1 = __builtin_amdgcn_mfma_f32_16x16x32_f16(A[1][1], B1, a1, 0, 0, 0);
            a2 = __builtin_amdgcn_mfma_f32_16x16x32_f16(A[2][1], B1, a2, 0, 0, 0);
            a3 = __builtin_amdgcn_mfma_f32_16x16x32_f16(A[3][1], B1, a3, 0, 0, 0);

            // prefetch x for next step (off the critical chain)
            const float xt_nxt = XT[t + 1][bl];

            // ---- select this lane's 2 accumulators ----
            float ga[4], gb[4];
            #pragma unroll
            for (int r = 0; r < 4; ++r) {
                ga[r] = db ? a1[r] : a0[r];
                gb[r] = db ? a3[r] : a2[r];
            }

            // ---- fused epilogue x2 (independent chains, interleave) ----
            {
                const float Ei = __builtin_amdgcn_exp2f(ga[0]);
                const float Ef = __builtin_amdgcn_exp2f(ga[1]);
                const float Eg = __builtin_amdgcn_exp2f(ga[2]);
                const float Eo = __builtin_amdgcn_exp2f(ga[3]);
                const float P  = (1.0f + Ei) * (1.0f + Eg);
                const float Q2 = __builtin_fmaf(LOG2E2, Ef, LOG2E2);
                const float num = __builtin_fmaf(c2A, P, (Eg - 1.0f) * Q2);
                const float PQ  = P * (1.0f + Ef);
                c2A = num * __builtin_amdgcn_rcpf(PQ);
                const float ca = fminf(c2A, 80.0f);
                const float Ec = __builtin_amdgcn_exp2f(ca);
                hA = (Ec - 1.0f) * __builtin_amdgcn_rcpf((1.0f + Eo) * (1.0f + Ec));
            }
            {
                const float Ei = __builtin_amdgcn_exp2f(gb[0]);
                const float Ef = __builtin_amdgcn_exp2f(gb[1]);
                const float Eg = __builtin_amdgcn_exp2f(gb[2]);
                const float Eo = __builtin_amdgcn_exp2f(gb[3]);
                const float P  = (1.0f + Ei) * (1.0f + Eg);
                const float Q2 = __builtin_fmaf(LOG2E2, Ef, LOG2E2);
                const float num = __builtin_fmaf(c2B, P, (Eg - 1.0f) * Q2);
                const float PQ  = P * (1.0f + Ef);
                c2B = num * __builtin_amdgcn_rcpf(PQ);
                const float ca = fminf(c2B, 80.0f);
                const float Ec = __builtin_amdgcn_exp2f(ca);
                hB = (Ec - 1.0f) * __builtin_amdgcn_rcpf((1.0f + Eo) * (1.0f + Ec));
            }

            // ---- two plain b16 writes (identity slots; pads self-zero) ----
            np[uA] = (_Float16)hA;
            np[uB] = (_Float16)hB;
            __syncthreads();
            xt_cur = xt_nxt;
        }
    }

    // ---- head: out[b] = b_lin + sum_j W_lin[j] * h[j][b] ----
    if (vA) redH[uA][bl] = wlA * hA;
    if (vB) redH[uB][bl] = wlB * hB;
    __syncthreads();
    if (tid < BW) {
        float s = b_lin[0];
        #pragma unroll 10
        for (int jj = 0; jj < H; ++jj) s += redH[jj][tid];
        out[b0 + tid] = s;
    }
}

extern "C" void kernel_launch(void* const* d_in, const int* in_sizes, int n_in,
                              void* d_out, int out_size, void* d_ws, size_t ws_size,
                              hipStream_t stream) {
    const float* x     = (const float*)d_in[0];
    const float* W_ih  = (const float*)d_in[1];
    const float* W_hh  = (const float*)d_in[2];
    const float* b_ih  = (const float*)d_in[3];
    const float* b_hh  = (const float*)d_in[4];
    const float* W_lin = (const float*)d_in[5];
    const float* b_lin = (const float*)d_in[6];
    float* out = (float*)d_out;

    dim3 grid(BATCH / BW);    // 256 blocks, 1 per CU
    dim3 block(NTHR);         // 4 waves
    lstm_kernel<<<grid, block, 0, stream>>>(x, W_ih, W_hh, b_ih, b_hh,
                                            W_lin, b_lin, out);
}